// Round 5
// baseline (727.247 us; speedup 1.0000x reference)
//
#include <hip/hip_runtime.h>

// GRU (B=4096, T=2048, H=8, I=4) + fused FC (O=4), fp32.
// R7: element-interleave (E=2) for ILP. Model update from R5/R6 numbers:
// per-SIMD issue = 2 cyc/inst (R5: 2 duplicated waves -> 2.06 cyc/inst,
// saturated), but ONE wave only sustains 4.3 cyc/inst (R6: 262 busy cyc for
// 61 inst) because the stream's ILP ~= 2 (short fma chains + serial
// sigmoid/tanh tail). Fix: each 16-lane row now carries TWO independent
// batch elements (2G, 2G+1) in separate register state with SHARED weights,
// steps issued back-to-back -> two independent dep chains, ILP ~4, bubbles
// filled with useful work instead of R5's duplicated work.
// 512 waves (half the SIMDs idle by design); win iff c(2) <= 2.6 cyc/inst.
// Carried from R6 (verified): gate-split r/z across the lane pair, row_ror
// depth-1 gather with (m-r)&7 pre-permuted weights, scale-folded
// sigmoid/tanh, hn = fma(-2*omz, u, fma(omz,1-h,h)), lagged FC reusing the
// gather, ping-pong x prefetch (PFD=4 per element), banked 16-dword stores.

#define GRU_T 2048
#define GRU_H 8
#define GRU_I 4
#define GRU_O 4
#define PFD   4        // per ping-pong half, per element; 2*PFD divides T

#define DPP_ROR(n) (0x120 + (n))   // row_ror:n : lane i <- lane (i-n)&15

template <int CTRL>
__device__ __forceinline__ float dpp_movf(float v) {
    return __int_as_float(
        __builtin_amdgcn_mov_dpp(__float_as_int(v), CTRL, 0xf, 0xf, true));
}

__device__ __forceinline__ float fast_rcp(float x)  { return __builtin_amdgcn_rcpf(x); }
__device__ __forceinline__ float fast_exp2(float x) { return __builtin_amdgcn_exp2f(x); }

__global__ __launch_bounds__(64, 1) void gru_fc_kernel(
    const float* __restrict__ x,
    const float* __restrict__ W_ih,
    const float* __restrict__ W_hh,
    const float* __restrict__ b_ih,
    const float* __restrict__ b_hh,
    const float* __restrict__ W_fc,
    const float* __restrict__ b_fc,
    float* __restrict__ out)
{
    const int tid = blockIdx.x * 64 + (int)threadIdx.x;
    const int G   = tid >> 4;            // lane-group id (4 per wave)
    const int q   = tid & 15;            // lane within group (one DPP row)
    const int g   = (q >> 3) & 1;        // 0: r-gate lane, 1: z-gate lane
    const int m   = q & 7;               // hidden index this lane owns
    const int o   = q & 3;               // FC output index (4x duplicated)
    const bool hi = (q & 8) != 0;

    const int eA = 2 * G;                // two independent elements per group
    const int eB = 2 * G + 1;

    // scale folding: sigma(a) = rcp(1+exp2(SR*a)); 1-sigma(a) =
    // rcp(1+exp2(SZ*a)); tanh(y) = 1 - 2*rcp(1+exp2(SN*y))
    const float SR = -1.4426950408889634f;
    const float SZ =  1.4426950408889634f;
    const float SN =  2.8853900817779268f;

    const float SG   = g ? SZ : SR;      // own-gate scale
    const int   gate = g ? 1 : 0;        // own-gate row block in W_*h

    // ---- weights: SHARED between the two elements ----
    float whA[8], whn[8], wf[8];
#pragma unroll
    for (int r = 0; r < 8; ++r) {
        const int k = (m - r) & 7;       // rot[r] holds h[(m-r)&7]
        whA[r] = SG * W_hh[(gate * GRU_H + m) * GRU_H + k];
        whn[r] = SN * W_hh[(2 * GRU_H + m) * GRU_H + k];
        wf[r]  = W_fc[o * GRU_H + k];
    }
    float wiA[4], win[4];
#pragma unroll
    for (int k = 0; k < 4; ++k) {
        wiA[k] = SG * W_ih[(gate * GRU_H + m) * GRU_I + k];
        win[k] = SN * W_ih[(2 * GRU_H + m) * GRU_I + k];
    }
    const float bA  = SG * (b_ih[gate * GRU_H + m] + b_hh[gate * GRU_H + m]);
    const float bxn = SN * b_ih[2 * GRU_H + m];
    const float bhn = SN * b_hh[2 * GRU_H + m];
    const float bo  = b_fc[o];

    // ---- per-element state ----
    float hprevA = 0.0f, bank0A = 0.0f, bank1A = 0.0f, bank2A = 0.0f;
    float hprevB = 0.0f, bank0B = 0.0f, bank1B = 0.0f, bank2B = 0.0f;

    const float4* __restrict__ xpA = reinterpret_cast<const float4*>(x) + (size_t)eA * GRU_T;
    const float4* __restrict__ xpB = reinterpret_cast<const float4*>(x) + (size_t)eB * GRU_T;
    float* __restrict__ opA = out + (size_t)eA * GRU_T * GRU_O + q;
    float* __restrict__ opB = out + (size_t)eB * GRU_T * GRU_O + q;

    float4 pingA[PFD], pongA[PFD], pingB[PFD], pongB[PFD];
#pragma unroll
    for (int j = 0; j < PFD; ++j) { pingA[j] = xpA[j]; pingB[j] = xpB[j]; }

#define GRU_STEP(S, XC, TCUR, JM)                                              \
    do {                                                                       \
        const float4 xc = (XC);                                                \
        const float xA_  = fmaf(wiA[1], xc.y, fmaf(wiA[0], xc.x, bA));         \
        const float xB_  = fmaf(wiA[3], xc.w, wiA[2] * xc.z);                  \
        const float xn_  = fmaf(win[3], xc.w, fmaf(win[2], xc.z,               \
                           fmaf(win[1], xc.y, fmaf(win[0], xc.x, bxn))));      \
        const float onemh = 1.0f - hprev##S;                                   \
        /* depth-1 rotation gather: rk = h_prev[(m-k)&7] */                    \
        const float r1 = dpp_movf<DPP_ROR(1)>(hprev##S);                       \
        const float r2 = dpp_movf<DPP_ROR(2)>(hprev##S);                       \
        const float r3 = dpp_movf<DPP_ROR(3)>(hprev##S);                       \
        const float r4 = dpp_movf<DPP_ROR(4)>(hprev##S);                       \
        const float r5 = dpp_movf<DPP_ROR(5)>(hprev##S);                       \
        const float r6 = dpp_movf<DPP_ROR(6)>(hprev##S);                       \
        const float r7 = dpp_movf<DPP_ROR(7)>(hprev##S);                       \
        /* own-gate hh dot: 4-leaf tree (g0 -> ar, g1 -> az) */                \
        const float tA = fmaf(whA[1], r1, fmaf(whA[0], hprev##S, xA_));        \
        const float tB = fmaf(whA[3], r3, fmaf(whA[2], r2, xB_));              \
        const float tC = fmaf(whA[5], r5, whA[4] * r4);                        \
        const float tD = fmaf(whA[7], r7, whA[6] * r6);                        \
        const float aOwn = (tA + tB) + (tC + tD);                              \
        /* one sigmoid per lane: g0 -> r, g1 -> omz = 1-z; exchange pair */    \
        const float sOwn = fast_rcp(1.0f + fast_exp2(aOwn));                   \
        const float sSib = dpp_movf<DPP_ROR(8)>(sOwn);                         \
        const float rg   = hi ? sSib : sOwn;                                   \
        const float omz  = hi ? sOwn : sSib;                                   \
        /* n-gate h dot */                                                     \
        const float nA = fmaf(whn[3], r3, fmaf(whn[2], r2,                     \
                         fmaf(whn[1], r1, fmaf(whn[0], hprev##S, bhn))));      \
        const float nB = fmaf(whn[7], r7, fmaf(whn[6], r6,                     \
                         fmaf(whn[5], r5, whn[4] * r4)));                      \
        const float ahn = nA + nB;                                             \
        /* lagged FC on h(t-1), reusing the rotation gather */                 \
        const float fA = fmaf(wf[3], r3, fmaf(wf[2], r2,                       \
                         fmaf(wf[1], r1, fmaf(wf[0], hprev##S, bo))));         \
        const float fB = fmaf(wf[7], r7, fmaf(wf[6], r6,                       \
                         fmaf(wf[5], r5, wf[4] * r4)));                        \
        const float fcv = fA + fB;                                             \
        /* tail */                                                             \
        const float c1  = fmaf(omz, onemh, hprev##S);                          \
        const float m2z = -2.0f * omz;                                         \
        const float yn  = fmaf(rg, ahn, xn_);                                  \
        const float u   = fast_rcp(1.0f + fast_exp2(yn));                      \
        hprev##S = fmaf(m2z, u, c1);     /* h + omz*(1-h) - 2*omz*u */         \
        /* bank fc by s=(t-1)&3; 16-dword flush per 4 steps */                 \
        if ((JM) == 1)      bank0##S = fcv;                                    \
        else if ((JM) == 2) bank1##S = fcv;                                    \
        else if ((JM) == 3) bank2##S = fcv;                                    \
        else if ((TCUR) != 0) {                                                \
            const float v01 = (q & 4) ? bank1##S : bank0##S;                   \
            const float v23 = (q & 4) ? fcv      : bank2##S;                   \
            const float val = (q & 8) ? v23      : v01;                        \
            op##S[(size_t)((TCUR) - 4) * GRU_O] = val;                         \
        }                                                                      \
    } while (0)

    for (int tb = 0; tb < GRU_T; tb += 2 * PFD) {
#pragma unroll
        for (int j = 0; j < PFD; ++j) {
            pongA[j] = xpA[tb + PFD + j];
            pongB[j] = xpB[tb + PFD + j];
        }
#pragma unroll
        for (int j = 0; j < PFD; ++j) {
            GRU_STEP(A, pingA[j], tb + j, j);
            GRU_STEP(B, pingB[j], tb + j, j);
        }
        const int tn = (tb + 2 * PFD) & (GRU_T - 1);   // wrap; values unused
#pragma unroll
        for (int j = 0; j < PFD; ++j) {
            pingA[j] = xpA[tn + j];
            pingB[j] = xpB[tn + j];
        }
#pragma unroll
        for (int j = 0; j < PFD; ++j) {
            GRU_STEP(A, pongA[j], tb + PFD + j, j);
            GRU_STEP(B, pongB[j], tb + PFD + j, j);
        }
    }

    // epilogue: flush lagged FC for steps T-4..T-1 of both elements
#define GRU_EPI(S)                                                             \
    do {                                                                       \
        const float r1 = dpp_movf<DPP_ROR(1)>(hprev##S);                       \
        const float r2 = dpp_movf<DPP_ROR(2)>(hprev##S);                       \
        const float r3 = dpp_movf<DPP_ROR(3)>(hprev##S);                       \
        const float r4 = dpp_movf<DPP_ROR(4)>(hprev##S);                       \
        const float r5 = dpp_movf<DPP_ROR(5)>(hprev##S);                       \
        const float r6 = dpp_movf<DPP_ROR(6)>(hprev##S);                       \
        const float r7 = dpp_movf<DPP_ROR(7)>(hprev##S);                       \
        const float fA = fmaf(wf[3], r3, fmaf(wf[2], r2,                       \
                         fmaf(wf[1], r1, fmaf(wf[0], hprev##S, bo))));         \
        const float fB = fmaf(wf[7], r7, fmaf(wf[6], r6,                       \
                         fmaf(wf[5], r5, wf[4] * r4)));                        \
        const float fcv = fA + fB;                                             \
        const float v01 = (q & 4) ? bank1##S : bank0##S;                       \
        const float v23 = (q & 4) ? fcv      : bank2##S;                       \
        const float val = (q & 8) ? v23      : v01;                            \
        op##S[(size_t)(GRU_T - 4) * GRU_O] = val;                              \
    } while (0)

    GRU_EPI(A);
    GRU_EPI(B);
#undef GRU_STEP
#undef GRU_EPI
}

extern "C" void kernel_launch(void* const* d_in, const int* in_sizes, int n_in,
                              void* d_out, int out_size, void* d_ws, size_t ws_size,
                              hipStream_t stream) {
    const float* x    = (const float*)d_in[0];
    const float* W_ih = (const float*)d_in[1];
    const float* W_hh = (const float*)d_in[2];
    const float* b_ih = (const float*)d_in[3];
    const float* b_hh = (const float*)d_in[4];
    const float* W_fc = (const float*)d_in[5];
    const float* b_fc = (const float*)d_in[6];
    float* out = (float*)d_out;

    const int B = in_sizes[0] / (GRU_T * GRU_I);       // 4096
    dim3 grid((unsigned)(B * 16 / (64 * 2))), block(64); // E=2 -> 512 waves
    hipLaunchKernelGGL(gru_fc_kernel, grid, block, 0, stream,
                       x, W_ih, W_hh, b_ih, b_hh, W_fc, b_fc, out);
}

// Round 7
// 499.538 us; speedup vs baseline: 1.4558x; 1.4558x over previous
//
#include <hip/hip_runtime.h>

// GRU (B=4096, T=2048, H=8, I=4) + fused FC (O=4), fp32.
// R9: R8's VOP3P packed-fp32 diet with the operand fix. v_pk_fma_f32 sources
// are 64-bit VGPR PAIRS (R8's "v"(float) fed a single reg -> "invalid
// operand"). op_sel_hi:[0,1,1] makes the HI lane of the result read src0's
// LO half (src0.hi never read), so we pass a pair with undefined hi word:
// the DPP-gathered scalar lands in the pair's low reg, no pair-forming movs.
// Machine law (R4-R7): wall = 4.6-5.5 cyc per wave-VALU-instruction,
// regardless of wave count (R5) or in-wave ILP (R7). Only lever: fewer
// instructions per wave-step. Packing:
//   - n-dot || FC-dot over {hprev, r1..r7}: weights {SN*Whh_n, Wfc},
//     acc {bhn, bo}: 8 pk_fma replaces ~17 scalar ops.
//   - gate-x || n-x over xc: 4 pk_fma replaces 8, acc {bA, bxn}.
// Stream ~61 -> ~49. All else carried from R6 (verified): gate-split r/z
// across the lane pair (1 sigmoid/lane + ror8 exchange), row_ror:1..7
// depth-1 gather with (m-r)&7 pre-permuted weights, scale-folded
// sigmoid/tanh, hn = fma(-2*omz, u, fma(omz,1-h,h)), lagged FC reusing the
// gather, ping-pong x prefetch, banked 16-dword stores.

#define GRU_T 2048
#define GRU_H 8
#define GRU_I 4
#define GRU_O 4
#define PFD   8        // per ping-pong half; 2*PFD must divide T

#define DPP_ROR(n) (0x120 + (n))   // row_ror:n : lane i <- lane (i-n)&15

typedef float v2f __attribute__((ext_vector_type(2)));

template <int CTRL>
__device__ __forceinline__ float dpp_movf(float v) {
    return __int_as_float(
        __builtin_amdgcn_mov_dpp(__float_as_int(v), CTRL, 0xf, 0xf, true));
}

// d.lo = fma(s, w.lo, acc.lo); d.hi = fma(s, w.hi, acc.hi) -- one VOP3P inst.
// src0 must be a VGPR pair; op_sel_hi:[0,1,1] broadcasts src0.lo to the hi
// op, so the pair's hi word is dead (left undefined on purpose).
__device__ __forceinline__ v2f pk_fma_s(float s, v2f w, v2f acc) {
    v2f sv;
    sv.x = s;                     // sv.y intentionally undefined (never read)
    v2f d;
    asm("v_pk_fma_f32 %0, %1, %2, %3 op_sel_hi:[0,1,1]"
        : "=v"(d) : "v"(sv), "v"(w), "v"(acc));
    return d;
}

__device__ __forceinline__ float fast_rcp(float x)  { return __builtin_amdgcn_rcpf(x); }
__device__ __forceinline__ float fast_exp2(float x) { return __builtin_amdgcn_exp2f(x); }

__global__ __launch_bounds__(64, 1) void gru_fc_kernel(
    const float* __restrict__ x,
    const float* __restrict__ W_ih,
    const float* __restrict__ W_hh,
    const float* __restrict__ b_ih,
    const float* __restrict__ b_hh,
    const float* __restrict__ W_fc,
    const float* __restrict__ b_fc,
    float* __restrict__ out)
{
    const int tid = blockIdx.x * 64 + (int)threadIdx.x;
    const int b   = tid >> 4;            // batch element (4 per wave)
    const int q   = tid & 15;            // lane within element (one DPP row)
    const int g   = (q >> 3) & 1;        // 0: r-gate lane, 1: z-gate lane
    const int m   = q & 7;               // hidden index this lane owns
    const int o   = q & 3;               // FC output index (4x duplicated)
    const bool hi = (q & 8) != 0;

    // scale folding: sigma(a) = rcp(1+exp2(SR*a)); 1-sigma(a) =
    // rcp(1+exp2(SZ*a)); tanh(y) = 1 - 2*rcp(1+exp2(SN*y))
    const float SR = -1.4426950408889634f;
    const float SZ =  1.4426950408889634f;
    const float SN =  2.8853900817779268f;

    const float SG   = g ? SZ : SR;      // own-gate scale
    const int   gate = g ? 1 : 0;        // own-gate row block in W_*h

    // ---- weights: own-gate scalar; {n, fc} and {gate-x, n-x} packed ----
    float whA[8];
    v2f   wnf[8];                        // {SN*Whh_n[m][k], Wfc[o][k]}
#pragma unroll
    for (int r = 0; r < 8; ++r) {
        const int k = (m - r) & 7;       // rot[r] holds h[(m-r)&7]
        whA[r]   = SG * W_hh[(gate * GRU_H + m) * GRU_H + k];
        wnf[r].x = SN * W_hh[(2 * GRU_H + m) * GRU_H + k];
        wnf[r].y = W_fc[o * GRU_H + k];
    }
    v2f wx[4];                           // {SG*W_ih[gate], SN*W_ih[n]}
#pragma unroll
    for (int k = 0; k < 4; ++k) {
        wx[k].x = SG * W_ih[(gate * GRU_H + m) * GRU_I + k];
        wx[k].y = SN * W_ih[(2 * GRU_H + m) * GRU_I + k];
    }
    v2f bx;                              // {bA (gate bias), bxn}
    bx.x = SG * (b_ih[gate * GRU_H + m] + b_hh[gate * GRU_H + m]);
    bx.y = SN * b_ih[2 * GRU_H + m];
    v2f bnf;                             // {bhn, bo}
    bnf.x = SN * b_hh[2 * GRU_H + m];
    bnf.y = b_fc[o];
    const float bo = bnf.y;

    float hprev = 0.0f;
    float bank0 = 0.0f, bank1 = 0.0f, bank2 = 0.0f;

    const float4* __restrict__ xp = reinterpret_cast<const float4*>(x) + (size_t)b * GRU_T;
    float* __restrict__ op = out + (size_t)b * GRU_T * GRU_O + q;

    float4 bufA[PFD], bufB[PFD];
#pragma unroll
    for (int j = 0; j < PFD; ++j) bufA[j] = xp[j];

#define GRU_STEP(XC, TCUR, JM)                                                 \
    do {                                                                       \
        const float4 xc = (XC);                                                \
        /* packed x-parts: {gate-x incl bias, n-x incl bxn}; h-independent */  \
        v2f xv = bx;                                                           \
        xv = pk_fma_s(xc.x, wx[0], xv);                                        \
        xv = pk_fma_s(xc.y, wx[1], xv);                                        \
        xv = pk_fma_s(xc.z, wx[2], xv);                                        \
        xv = pk_fma_s(xc.w, wx[3], xv);                                        \
        const float xOwn = xv.x;                                               \
        const float xn_  = xv.y;                                               \
        const float onemh = 1.0f - hprev;                                      \
        /* depth-1 rotation gather: rk = h_prev[(m-k)&7] */                    \
        const float r1 = dpp_movf<DPP_ROR(1)>(hprev);                          \
        const float r2 = dpp_movf<DPP_ROR(2)>(hprev);                          \
        const float r3 = dpp_movf<DPP_ROR(3)>(hprev);                          \
        const float r4 = dpp_movf<DPP_ROR(4)>(hprev);                          \
        const float r5 = dpp_movf<DPP_ROR(5)>(hprev);                          \
        const float r6 = dpp_movf<DPP_ROR(6)>(hprev);                          \
        const float r7 = dpp_movf<DPP_ROR(7)>(hprev);                          \
        /* own-gate hh dot: 4-leaf scalar tree (g0 -> ar, g1 -> az) */         \
        const float tA = fmaf(whA[1], r1, fmaf(whA[0], hprev, xOwn));          \
        const float tB = fmaf(whA[3], r3, whA[2] * r2);                        \
        const float tC = fmaf(whA[5], r5, whA[4] * r4);                        \
        const float tD = fmaf(whA[7], r7, whA[6] * r6);                        \
        const float aOwn = (tA + tB) + (tC + tD);                              \
        /* one sigmoid per lane: g0 -> r, g1 -> omz = 1-z; exchange pair */    \
        const float sOwn = fast_rcp(1.0f + fast_exp2(aOwn));                   \
        const float sSib = dpp_movf<DPP_ROR(8)>(sOwn);                         \
        const float rg   = hi ? sSib : sOwn;                                   \
        const float omz  = hi ? sOwn : sSib;                                   \
        /* packed {n-dot, fc-dot} over the same gathered h (8 pk_fma) */       \
        v2f nf = bnf;                                                          \
        nf = pk_fma_s(hprev, wnf[0], nf);                                      \
        nf = pk_fma_s(r1,    wnf[1], nf);                                      \
        nf = pk_fma_s(r2,    wnf[2], nf);                                      \
        nf = pk_fma_s(r3,    wnf[3], nf);                                      \
        nf = pk_fma_s(r4,    wnf[4], nf);                                      \
        nf = pk_fma_s(r5,    wnf[5], nf);                                      \
        nf = pk_fma_s(r6,    wnf[6], nf);                                      \
        nf = pk_fma_s(r7,    wnf[7], nf);                                      \
        const float ahn = nf.x;                                                \
        const float fcv = nf.y;          /* lagged FC on h(t-1) */             \
        /* tail: exp add rcp, fma, fma */                                      \
        const float c1  = fmaf(omz, onemh, hprev);                             \
        const float m2z = -2.0f * omz;                                         \
        const float yn  = fmaf(rg, ahn, xn_);                                  \
        const float u   = fast_rcp(1.0f + fast_exp2(yn));                      \
        hprev = fmaf(m2z, u, c1);        /* h + omz*(1-h) - 2*omz*u */         \
        /* bank fc by s=(t-1)&3; store 4 steps per 16-dword chunk */           \
        if (((JM) & 3) == 1)      bank0 = fcv;                                 \
        else if (((JM) & 3) == 2) bank1 = fcv;                                 \
        else if (((JM) & 3) == 3) bank2 = fcv;                                 \
        else if ((TCUR) != 0) {                                                \
            const float v01 = (q & 4) ? bank1 : bank0;                         \
            const float v23 = (q & 4) ? fcv   : bank2;                         \
            const float val = (q & 8) ? v23   : v01;                           \
            op[(size_t)((TCUR) - 4) * GRU_O] = val;                            \
        }                                                                      \
    } while (0)

    for (int tb = 0; tb < GRU_T; tb += 2 * PFD) {
#pragma unroll
        for (int j = 0; j < PFD; ++j) bufB[j] = xp[tb + PFD + j];
#pragma unroll
        for (int j = 0; j < PFD; ++j) GRU_STEP(bufA[j], tb + j, j);
        const int tn = (tb + 2 * PFD) & (GRU_T - 1);   // wrap; values unused
#pragma unroll
        for (int j = 0; j < PFD; ++j) bufA[j] = xp[tn + j];
#pragma unroll
        for (int j = 0; j < PFD; ++j) GRU_STEP(bufB[j], tb + PFD + j, j);
    }

    // epilogue: flush lagged FC for step T-1 (h = final hprev)
    {
        const float r1 = dpp_movf<DPP_ROR(1)>(hprev);
        const float r2 = dpp_movf<DPP_ROR(2)>(hprev);
        const float r3 = dpp_movf<DPP_ROR(3)>(hprev);
        const float r4 = dpp_movf<DPP_ROR(4)>(hprev);
        const float r5 = dpp_movf<DPP_ROR(5)>(hprev);
        const float r6 = dpp_movf<DPP_ROR(6)>(hprev);
        const float r7 = dpp_movf<DPP_ROR(7)>(hprev);
        const float fA = fmaf(wnf[3].y, r3, fmaf(wnf[2].y, r2,
                         fmaf(wnf[1].y, r1, fmaf(wnf[0].y, hprev, bo))));
        const float fB = fmaf(wnf[7].y, r7, fmaf(wnf[6].y, r6,
                         fmaf(wnf[5].y, r5, wnf[4].y * r4)));
        const float fcv = fA + fB;
        const float v01 = (q & 4) ? bank1 : bank0;
        const float v23 = (q & 4) ? fcv   : bank2;
        const float val = (q & 8) ? v23   : v01;
        op[(size_t)(GRU_T - 4) * GRU_O] = val;
    }
#undef GRU_STEP
}

extern "C" void kernel_launch(void* const* d_in, const int* in_sizes, int n_in,
                              void* d_out, int out_size, void* d_ws, size_t ws_size,
                              hipStream_t stream) {
    const float* x    = (const float*)d_in[0];
    const float* W_ih = (const float*)d_in[1];
    const float* W_hh = (const float*)d_in[2];
    const float* b_ih = (const float*)d_in[3];
    const float* b_hh = (const float*)d_in[4];
    const float* W_fc = (const float*)d_in[5];
    const float* b_fc = (const float*)d_in[6];
    float* out = (float*)d_out;

    const int B = in_sizes[0] / (GRU_T * GRU_I);   // 4096
    dim3 grid((unsigned)(B * 16 / 64)), block(64); // 16 lanes/elem, 1024 waves
    hipLaunchKernelGGL(gru_fc_kernel, grid, block, 0, stream,
                       x, W_ih, W_hh, b_ih, b_hh, W_fc, b_fc, out);
}

// Round 8
// 395.993 us; speedup vs baseline: 1.8365x; 1.2615x over previous
//
#include <hip/hip_runtime.h>

// GRU (B=4096, T=2048, H=8, I=4) + fused FC (O=4), fp32.
// R10: packed fp32 via COMPILER-generated VOP3P (no inline asm). R9 proved
// packing cuts busy cycles exactly as the inst-count law predicts (211 =
// ~49 inst x 4.3), but its 8-deep serial asm chain exposed ~150 cyc of
// VOP3P dependent latency (~12 cyc/link). Fix, keeping the diet:
//  - plain v2f (ext_vector) math + __builtin_elementwise_fma -> LLVM emits
//    v_pk_fma_f32 / v_pk_mul_f32 with full scheduling freedom.
//  - zero broadcast movs: value pairs P0={h,r1} P1={r2,r3} P2={r4,r5}
//    P3={r6,r7} are built by pointing the 7 existing DPP movs at pair
//    halves; weights are preloaded in matching pair order.
//  - each dot (own-gate, n, FC) = two INDEPENDENT 2-deep pk chains +
//    pk_add + horizontal add; biases folded into loop-invariant {bias,0}
//    accumulator-init pairs. Max h-dependent pk depth 2 (R9 was 12).
//  - x-parts packed over natural pairs {xc.x,xc.y},{xc.z,xc.w}.
//  - tail trim: u2 = rcp(fma(0.5,e,0.5)) = 2u, hn = fma(-omz,u2,c1)
//    (neg modifier free) deletes the -2*omz mul.
// Stream ~61 -> ~48. All else carried from R6 (verified): gate-split r/z
// across the lane pair (1 sigmoid/lane + ror8 exchange + 2 cndmask),
// row_ror:1..7 depth-1 gather with (m-r)&7 pre-permuted weights,
// scale-folded sigmoid/tanh, lagged FC reusing the gather, ping-pong x
// prefetch, banked 16-dword stores.

#define GRU_T 2048
#define GRU_H 8
#define GRU_I 4
#define GRU_O 4
#define PFD   8        // per ping-pong half; 2*PFD must divide T

#define DPP_ROR(n) (0x120 + (n))   // row_ror:n : lane i <- lane (i-n)&15

typedef float v2f __attribute__((ext_vector_type(2)));
#define FMA2(a, b, c) __builtin_elementwise_fma((a), (b), (c))

template <int CTRL>
__device__ __forceinline__ float dpp_movf(float v) {
    return __int_as_float(
        __builtin_amdgcn_mov_dpp(__float_as_int(v), CTRL, 0xf, 0xf, true));
}

__device__ __forceinline__ float fast_rcp(float x)  { return __builtin_amdgcn_rcpf(x); }
__device__ __forceinline__ float fast_exp2(float x) { return __builtin_amdgcn_exp2f(x); }

__global__ __launch_bounds__(64, 1) void gru_fc_kernel(
    const float* __restrict__ x,
    const float* __restrict__ W_ih,
    const float* __restrict__ W_hh,
    const float* __restrict__ b_ih,
    const float* __restrict__ b_hh,
    const float* __restrict__ W_fc,
    const float* __restrict__ b_fc,
    float* __restrict__ out)
{
    const int tid = blockIdx.x * 64 + (int)threadIdx.x;
    const int b   = tid >> 4;            // batch element (4 per wave)
    const int q   = tid & 15;            // lane within element (one DPP row)
    const int g   = (q >> 3) & 1;        // 0: r-gate lane, 1: z-gate lane
    const int m   = q & 7;               // hidden index this lane owns
    const int o   = q & 3;               // FC output index (4x duplicated)
    const bool hi = (q & 8) != 0;

    // scale folding: sigma(a) = rcp(1+exp2(SR*a)); 1-sigma(a) =
    // rcp(1+exp2(SZ*a)); tanh(y) = 1 - 2*rcp(1+exp2(SN*y))
    const float SR = -1.4426950408889634f;
    const float SZ =  1.4426950408889634f;
    const float SN =  2.8853900817779268f;

    const float SG   = g ? SZ : SR;      // own-gate scale
    const int   gate = g ? 1 : 0;        // own-gate row block in W_*h

    // ---- weights as pairs matching P_j = {rot[2j], rot[2j+1]} ----
    v2f wA[4], wn[4], wfp[4];
#pragma unroll
    for (int j = 0; j < 4; ++j) {
        const int k0 = (m - 2 * j) & 7;      // partner of P_j.x
        const int k1 = (m - 2 * j - 1) & 7;  // partner of P_j.y
        wA[j].x  = SG * W_hh[(gate * GRU_H + m) * GRU_H + k0];
        wA[j].y  = SG * W_hh[(gate * GRU_H + m) * GRU_H + k1];
        wn[j].x  = SN * W_hh[(2 * GRU_H + m) * GRU_H + k0];
        wn[j].y  = SN * W_hh[(2 * GRU_H + m) * GRU_H + k1];
        wfp[j].x = W_fc[o * GRU_H + k0];
        wfp[j].y = W_fc[o * GRU_H + k1];
    }
    v2f wxA[2], wxn[2];
#pragma unroll
    for (int j = 0; j < 2; ++j) {
        wxA[j].x = SG * W_ih[(gate * GRU_H + m) * GRU_I + 2 * j];
        wxA[j].y = SG * W_ih[(gate * GRU_H + m) * GRU_I + 2 * j + 1];
        wxn[j].x = SN * W_ih[(2 * GRU_H + m) * GRU_I + 2 * j];
        wxn[j].y = SN * W_ih[(2 * GRU_H + m) * GRU_I + 2 * j + 1];
    }
    // loop-invariant accumulator-init pairs {bias, 0}
    v2f BA, Bxn, Bn, Bf;
    BA.x  = SG * (b_ih[gate * GRU_H + m] + b_hh[gate * GRU_H + m]); BA.y  = 0.0f;
    Bxn.x = SN * b_ih[2 * GRU_H + m];                               Bxn.y = 0.0f;
    Bn.x  = SN * b_hh[2 * GRU_H + m];                               Bn.y  = 0.0f;
    Bf.x  = b_fc[o];                                                Bf.y  = 0.0f;

    float hprev = 0.0f;
    float bank0 = 0.0f, bank1 = 0.0f, bank2 = 0.0f;

    const float4* __restrict__ xp = reinterpret_cast<const float4*>(x) + (size_t)b * GRU_T;
    float* __restrict__ op = out + (size_t)b * GRU_T * GRU_O + q;

    float4 bufA[PFD], bufB[PFD];
#pragma unroll
    for (int j = 0; j < PFD; ++j) bufA[j] = xp[j];

#define GRU_STEP(XC, TCUR, JM)                                                 \
    do {                                                                       \
        const float4 xc = (XC);                                                \
        v2f x01; x01.x = xc.x; x01.y = xc.y;                                   \
        v2f x23; x23.x = xc.z; x23.y = xc.w;                                   \
        /* packed x-parts (h-independent, fill latency shadows) */             \
        v2f xa = FMA2(x01, wxA[0], BA);   xa = FMA2(x23, wxA[1], xa);          \
        v2f xv = FMA2(x01, wxn[0], Bxn);  xv = FMA2(x23, wxn[1], xv);          \
        const float xn_  = xv.x + xv.y;                                        \
        const float onemh = 1.0f - hprev;                                      \
        /* depth-1 rotation gather into pair halves: zero extra movs */        \
        v2f P0, P1, P2, P3;                                                    \
        P0.x = hprev;                                                          \
        P0.y = dpp_movf<DPP_ROR(1)>(hprev);                                    \
        P1.x = dpp_movf<DPP_ROR(2)>(hprev);                                    \
        P1.y = dpp_movf<DPP_ROR(3)>(hprev);                                    \
        P2.x = dpp_movf<DPP_ROR(4)>(hprev);                                    \
        P2.y = dpp_movf<DPP_ROR(5)>(hprev);                                    \
        P3.x = dpp_movf<DPP_ROR(6)>(hprev);                                    \
        P3.y = dpp_movf<DPP_ROR(7)>(hprev);                                    \
        /* own-gate dot: two 2-deep pk chains (g0 -> ar, g1 -> az) */          \
        v2f oA = FMA2(P0, wA[0], xa);  oA = FMA2(P1, wA[1], oA);               \
        v2f oB = P2 * wA[2];           oB = FMA2(P3, wA[3], oB);               \
        const v2f oS = oA + oB;                                                \
        const float aOwn = oS.x + oS.y;                                        \
        /* one sigmoid per lane: g0 -> r, g1 -> omz = 1-z; exchange pair */    \
        const float sOwn = fast_rcp(1.0f + fast_exp2(aOwn));                   \
        const float sSib = dpp_movf<DPP_ROR(8)>(sOwn);                         \
        const float rg   = hi ? sSib : sOwn;                                   \
        const float omz  = hi ? sOwn : sSib;                                   \
        /* n-gate h dot: two 2-deep pk chains */                               \
        v2f nA = FMA2(P0, wn[0], Bn);  nA = FMA2(P1, wn[1], nA);               \
        v2f nB = P2 * wn[2];           nB = FMA2(P3, wn[3], nB);               \
        const v2f nS = nA + nB;                                                \
        const float ahn = nS.x + nS.y;                                         \
        /* lagged FC on h(t-1), same pairs */                                  \
        v2f fA = FMA2(P0, wfp[0], Bf); fA = FMA2(P1, wfp[1], fA);              \
        v2f fB = P2 * wfp[2];          fB = FMA2(P3, wfp[3], fB);              \
        const v2f fS = fA + fB;                                                \
        const float fcv = fS.x + fS.y;                                         \
        /* tail: u2 = 2/(1+exp2(yn)); hn = c1 - omz*u2 (free neg mod) */       \
        const float c1 = fmaf(omz, onemh, hprev);                              \
        const float yn = fmaf(rg, ahn, xn_);                                   \
        const float e  = fast_exp2(yn);                                        \
        const float u2 = fast_rcp(fmaf(0.5f, e, 0.5f));                        \
        hprev = fmaf(-omz, u2, c1);                                            \
        /* bank fc by s=(t-1)&3; store 4 steps per 16-dword chunk */           \
        if (((JM) & 3) == 1)      bank0 = fcv;                                 \
        else if (((JM) & 3) == 2) bank1 = fcv;                                 \
        else if (((JM) & 3) == 3) bank2 = fcv;                                 \
        else if ((TCUR) != 0) {                                                \
            const float v01 = (q & 4) ? bank1 : bank0;                         \
            const float v23 = (q & 4) ? fcv   : bank2;                         \
            const float val = (q & 8) ? v23   : v01;                           \
            op[(size_t)((TCUR) - 4) * GRU_O] = val;                            \
        }                                                                      \
    } while (0)

    for (int tb = 0; tb < GRU_T; tb += 2 * PFD) {
#pragma unroll
        for (int j = 0; j < PFD; ++j) bufB[j] = xp[tb + PFD + j];
#pragma unroll
        for (int j = 0; j < PFD; ++j) GRU_STEP(bufA[j], tb + j, j);
        const int tn = (tb + 2 * PFD) & (GRU_T - 1);   // wrap; values unused
#pragma unroll
        for (int j = 0; j < PFD; ++j) bufA[j] = xp[tn + j];
#pragma unroll
        for (int j = 0; j < PFD; ++j) GRU_STEP(bufB[j], tb + PFD + j, j);
    }

    // epilogue: flush lagged FC for step T-1 (h = final hprev)
    {
        v2f P0, P1, P2, P3;
        P0.x = hprev;
        P0.y = dpp_movf<DPP_ROR(1)>(hprev);
        P1.x = dpp_movf<DPP_ROR(2)>(hprev);
        P1.y = dpp_movf<DPP_ROR(3)>(hprev);
        P2.x = dpp_movf<DPP_ROR(4)>(hprev);
        P2.y = dpp_movf<DPP_ROR(5)>(hprev);
        P3.x = dpp_movf<DPP_ROR(6)>(hprev);
        P3.y = dpp_movf<DPP_ROR(7)>(hprev);
        v2f fA = FMA2(P0, wfp[0], Bf); fA = FMA2(P1, wfp[1], fA);
        v2f fB = P2 * wfp[2];          fB = FMA2(P3, wfp[3], fB);
        const v2f fS = fA + fB;
        const float fcv = fS.x + fS.y;
        const float v01 = (q & 4) ? bank1 : bank0;
        const float v23 = (q & 4) ? fcv   : bank2;
        const float val = (q & 8) ? v23   : v01;
        op[(size_t)(GRU_T - 4) * GRU_O] = val;
    }
#undef GRU_STEP
}

extern "C" void kernel_launch(void* const* d_in, const int* in_sizes, int n_in,
                              void* d_out, int out_size, void* d_ws, size_t ws_size,
                              hipStream_t stream) {
    const float* x    = (const float*)d_in[0];
    const float* W_ih = (const float*)d_in[1];
    const float* W_hh = (const float*)d_in[2];
    const float* b_ih = (const float*)d_in[3];
    const float* b_hh = (const float*)d_in[4];
    const float* W_fc = (const float*)d_in[5];
    const float* b_fc = (const float*)d_in[6];
    float* out = (float*)d_out;

    const int B = in_sizes[0] / (GRU_T * GRU_I);   // 4096
    dim3 grid((unsigned)(B * 16 / 64)), block(64); // 16 lanes/elem, 1024 waves
    hipLaunchKernelGGL(gru_fc_kernel, grid, block, 0, stream,
                       x, W_ih, W_hh, b_ih, b_hh, W_fc, b_fc, out);
}